// Round 4
// baseline (90.571 us; speedup 1.0000x reference)
//
#include <hip/hip_runtime.h>

// Problem dims (fixed by reference)
#define BB 4
#define LL 1024
#define DD 64
#define UU 32
#define TI 8     // query rows per block (attn)
#define NT 512   // threads per block (8 waves)
#define PR 16    // rows per precompute block

// ---------------------------------------------------------------------------
// Packed fp32 via compiler-selected VOP3P: on gfx90a+ LLVM lowers <2 x float>
// fma/mul to v_pk_fma_f32 / v_pk_mul_f32 (2 fp32 ops per issue slot — the
// only path to the 157 TF fp32 peak; scalar v_fma is half rate). No inline
// asm: correctness identical to scalar IEEE fma per lane.
// ---------------------------------------------------------------------------
typedef float f32x2 __attribute__((ext_vector_type(2)));
#define FMA2(a, b, c) __builtin_elementwise_fma((a), (b), (c))
static __device__ __forceinline__ f32x2 splat2(float x) { return (f32x2){x, x}; }

// ---------------------------------------------------------------------------
// K1: Eq[b,l,u] = exp(2*(inp@Wt + bh))   (layout [row][u], scalar-loaded later)
//     Ekt[b,u4,j] = float4 of exp(2*(inp@Wx))  (TRANSPOSED: lane-consecutive
//     j -> coalesced float4 loads in attn phase A)
// tanh(q+k+bh) = 1 - 2/(1 + Eq*Ek)
// v5: 16 rows/block, 512 threads, 256 blocks — halves block count and
// weight-staging traffic per row (latency/launch-dominated kernel).
// ---------------------------------------------------------------------------
__global__ __launch_bounds__(512) void precompute_kernel(
    const float* __restrict__ inp, const float* __restrict__ Wt,
    const float* __restrict__ Wx, const float* __restrict__ bh,
    float* __restrict__ Eq, float* __restrict__ Ekt)
{
    __shared__ float s_in[PR][DD];      // 4 KB
    __shared__ float s_wt[DD][UU];      // 8 KB
    __shared__ float s_wx[DD][UU];      // 8 KB
    __shared__ float s_ek[PR][36];      // padded: conflict-free b128 reads
    int t = threadIdx.x;
    int row0 = blockIdx.x * PR;
    ((float4*)s_wt)[t] = ((const float4*)Wt)[t];          // 512 float4 each
    ((float4*)s_wx)[t] = ((const float4*)Wx)[t];
    if (t < 256)
        ((float4*)s_in)[t] = ((const float4*)(inp + (size_t)row0 * DD))[t];
    __syncthreads();
    int r = t >> 5;     // 0..15
    int u = t & 31;
    size_t row = row0 + r;
    float q = 0.f, k = 0.f;
#pragma unroll
    for (int d = 0; d < DD; ++d) {
        float x = s_in[r][d];
        q = fmaf(x, s_wt[d][u], q);
        k = fmaf(x, s_wx[d][u], k);
    }
    Eq[row * UU + u] = __expf(2.f * (q + bh[u]));
    s_ek[r][u] = __expf(2.f * k);
    __syncthreads();
    // transposed write: Ekt[(b*8 + u4)*LL + l] (float4 units)
    if (t < 128) {
        int u4 = t >> 4, r2 = t & 15;
        float4 v = *(const float4*)(&s_ek[r2][u4 * 4]);
        size_t gr = row0 + r2;
        size_t bb_ = gr >> 10, l = gr & 1023;
        ((float4*)Ekt)[(bb_ * 8 + u4) * LL + l] = v;
    }
}

// ---------------------------------------------------------------------------
// K2: fused scores -> softmax -> v, TI=8 rows/block, 512 threads.
// grid = B*L/TI = 512 blocks (2/CU).
// v5 changes vs v4 (88.7 us):
//  * Phase A regrouped: acc += n01*rcp(pq) + n23*rcp(rs) — 12 packed VALU +
//    4 TRANS rcp per (i,u4) instead of 14 + 2. TRANS co-issues with VALU
//    (separate sched class), VALU is the binding pipe -> ~14% fewer issues.
//    Also numerically safer (pq <= ~1e11 vs den <= ~1e22) and shorter chains.
//  * Phase B: 4-deep rolling register prefetch of the x float4s; first 4
//    issued BEFORE barrier B1 (drain overlaps staging), loop fully unrolled
//    so buffer indices are static (no scratch).
// ---------------------------------------------------------------------------
__global__ __launch_bounds__(NT, 4) void attn_kernel(
    const float* __restrict__ Eq, const float* __restrict__ Ekt,
    const float* __restrict__ inp, const float* __restrict__ Wa,
    float* __restrict__ out)
{
    __shared__ float s_a0[LL][4];          // 16 KB: a_unnorm[j][i0..3]
    __shared__ float s_a1[LL][4];          // 16 KB: a_unnorm[j][i4..7]
    __shared__ float4 s_v[8][TI][16];      // 16 KB: v partials [wave][i][dq]
    __shared__ float s_red[8][TI];         // wave partial sums

    int t  = threadIdx.x;
    int w  = t >> 6;                    // wave 0..7
    int b  = blockIdx.x >> 7;
    int i0 = (blockIdx.x & 127) * TI;

    const float4* ektb = (const float4*)Ekt + (size_t)b * 8 * LL;
    const float*  eqb  = Eq + ((size_t)(b * LL + i0)) * UU;   // block-uniform

    // ---------------- Phase A: scores, Ek register-resident as jj-pairs -----
    f32x2 ekp[8][4];                    // ekp[u4][c] = {Ek[j=t][c], Ek[j=t+512][c]}
#pragma unroll
    for (int u4 = 0; u4 < 8; ++u4) {
        float4 e0 = ektb[u4 * LL + t];
        float4 e1 = ektb[u4 * LL + NT + t];
        ekp[u4][0] = (f32x2){e0.x, e1.x};
        ekp[u4][1] = (f32x2){e0.y, e1.y};
        ekp[u4][2] = (f32x2){e0.z, e1.z};
        ekp[u4][3] = (f32x2){e0.w, e1.w};
    }

    const f32x2 ones = (f32x2){1.f, 1.f};
    f32x2 acc2[TI];
#pragma unroll
    for (int i = 0; i < TI; ++i) {
        acc2[i] = (f32x2){0.f, 0.f};
        const float* eqq = eqb + i * UU;                  // uniform s_loads
#pragma unroll
        for (int u4 = 0; u4 < 8; ++u4) {
            const float* waq = Wa + u4 * 4;               // uniform, CSEd
            f32x2 p = FMA2(splat2(eqq[u4 * 4 + 0]), ekp[u4][0], ones);
            f32x2 q = FMA2(splat2(eqq[u4 * 4 + 1]), ekp[u4][1], ones);
            f32x2 r = FMA2(splat2(eqq[u4 * 4 + 2]), ekp[u4][2], ones);
            f32x2 s = FMA2(splat2(eqq[u4 * 4 + 3]), ekp[u4][3], ones);
            // n01 = wa0*q + wa1*p ; n23 = wa2*s + wa3*r
            f32x2 n01 = FMA2(splat2(waq[0]), q, splat2(waq[1]) * p);
            f32x2 n23 = FMA2(splat2(waq[2]), s, splat2(waq[3]) * r);
            f32x2 pq  = p * q;                            // >= 1, <= ~1e22^0.5
            f32x2 rs2 = r * s;
            f32x2 rq, rr;
            rq.x = __builtin_amdgcn_rcpf(pq.x);           // TRANS pipe
            rq.y = __builtin_amdgcn_rcpf(pq.y);
            rr.x = __builtin_amdgcn_rcpf(rs2.x);
            rr.y = __builtin_amdgcn_rcpf(rs2.y);
            acc2[i] = FMA2(n01, rq, acc2[i]);
            acc2[i] = FMA2(n23, rr, acc2[i]);
        }
    }

    // ---------------- exp (no max-sub: |arg| <= ~6) + single sum reduce -----
    float wsum[TI];
#pragma unroll
    for (int i = 0; i < TI; ++i) {
        float e0 = __expf(-2.f * acc2[i].x);
        float e1 = __expf(-2.f * acc2[i].y);
        acc2[i].x = e0;
        acc2[i].y = e1;
        float s = e0 + e1;
#pragma unroll
        for (int mm = 32; mm >= 1; mm >>= 1) s += __shfl_xor(s, mm, 64);
        wsum[i] = s;
    }
    if ((t & 63) == 0) {
#pragma unroll
        for (int i = 0; i < TI; ++i) s_red[w][i] = wsum[i];
    }

    // Phase-B x prefetch: issue BEFORE B1 so the barrier's vmcnt drain
    // overlaps staging; values stay in VGPRs (16 regs, ekp dead by now).
    int dq = t & 15;        // d-quad
    int g  = t >> 4;        // j-group 0..31
    const float4* inp4 = (const float4*)(inp + (size_t)b * LL * DD);
    float4 xpre[4];
#pragma unroll
    for (int pf = 0; pf < 4; ++pf)
        xpre[pf] = inp4[((pf * 32 + g) * 16) + dq];

    // stage UNNORMALIZED exp (normalization deferred to final output scale)
    {
        float4 lo, hi;
        lo.x = acc2[0].x; lo.y = acc2[1].x; lo.z = acc2[2].x; lo.w = acc2[3].x;
        hi.x = acc2[4].x; hi.y = acc2[5].x; hi.z = acc2[6].x; hi.w = acc2[7].x;
        *(float4*)(&s_a0[t][0]) = lo;
        *(float4*)(&s_a1[t][0]) = hi;
        lo.x = acc2[0].y; lo.y = acc2[1].y; lo.z = acc2[2].y; lo.w = acc2[3].y;
        hi.x = acc2[4].y; hi.y = acc2[5].y; hi.z = acc2[6].y; hi.w = acc2[7].y;
        *(float4*)(&s_a0[NT + t][0]) = lo;
        *(float4*)(&s_a1[NT + t][0]) = hi;
    }
    __syncthreads();                                             // B1

    // ---------------- Phase B: v = ex @ inputs (a-paired packed fp32) -------
    // vac[c][p] = { sum_j a[2p]  * x_c , sum_j a[2p+1] * x_c }
    f32x2 vac[4][4];
#pragma unroll
    for (int c = 0; c < 4; ++c)
#pragma unroll
        for (int p_ = 0; p_ < 4; ++p_) vac[c][p_] = (f32x2){0.f, 0.f};

#pragma unroll
    for (int jj = 0; jj < 32; ++jj) {
        int j = jj * 32 + g;
        float4 x = xpre[jj & 3];
        if (jj + 4 < 32)
            xpre[jj & 3] = inp4[(((jj + 4) * 32 + g) * 16) + dq];
        float4 a0 = *(const float4*)(&s_a0[j][0]);   // b128 broadcast
        float4 a1 = *(const float4*)(&s_a1[j][0]);
        f32x2 ap0 = (f32x2){a0.x, a0.y};             // natural reg pairs
        f32x2 ap1 = (f32x2){a0.z, a0.w};
        f32x2 ap2 = (f32x2){a1.x, a1.y};
        f32x2 ap3 = (f32x2){a1.z, a1.w};
        f32x2 xs;
        xs = splat2(x.x);
        vac[0][0] = FMA2(ap0, xs, vac[0][0]); vac[0][1] = FMA2(ap1, xs, vac[0][1]);
        vac[0][2] = FMA2(ap2, xs, vac[0][2]); vac[0][3] = FMA2(ap3, xs, vac[0][3]);
        xs = splat2(x.y);
        vac[1][0] = FMA2(ap0, xs, vac[1][0]); vac[1][1] = FMA2(ap1, xs, vac[1][1]);
        vac[1][2] = FMA2(ap2, xs, vac[1][2]); vac[1][3] = FMA2(ap3, xs, vac[1][3]);
        xs = splat2(x.z);
        vac[2][0] = FMA2(ap0, xs, vac[2][0]); vac[2][1] = FMA2(ap1, xs, vac[2][1]);
        vac[2][2] = FMA2(ap2, xs, vac[2][2]); vac[2][3] = FMA2(ap3, xs, vac[2][3]);
        xs = splat2(x.w);
        vac[3][0] = FMA2(ap0, xs, vac[3][0]); vac[3][1] = FMA2(ap1, xs, vac[3][1]);
        vac[3][2] = FMA2(ap2, xs, vac[3][2]); vac[3][3] = FMA2(ap3, xs, vac[3][3]);
    }

    // unwind a-pairing back to per-row float4s: v[i].c = vac[c][i>>1][i&1]
    float4 v[TI];
#pragma unroll
    for (int i = 0; i < TI; ++i) {
        int p_ = i >> 1;
        if (i & 1)
            v[i] = (float4){vac[0][p_].y, vac[1][p_].y, vac[2][p_].y, vac[3][p_].y};
        else
            v[i] = (float4){vac[0][p_].x, vac[1][p_].x, vac[2][p_].x, vac[3][p_].x};
    }

    // reduce 4 j-groups within each wave (lanes differ in bits 4,5 of t)
#pragma unroll
    for (int i = 0; i < TI; ++i) {
        v[i].x += __shfl_xor(v[i].x, 16, 64); v[i].y += __shfl_xor(v[i].y, 16, 64);
        v[i].z += __shfl_xor(v[i].z, 16, 64); v[i].w += __shfl_xor(v[i].w, 16, 64);
        v[i].x += __shfl_xor(v[i].x, 32, 64); v[i].y += __shfl_xor(v[i].y, 32, 64);
        v[i].z += __shfl_xor(v[i].z, 32, 64); v[i].w += __shfl_xor(v[i].w, 32, 64);
    }
    if ((t & 63) < 16) {
#pragma unroll
        for (int i = 0; i < TI; ++i) s_v[w][i][dq] = v[i];
    }
    __syncthreads();                                             // B2

    // final cross-wave reduce + deferred normalization + coalesced store
    int i = t >> 6;       // 0..7
    int d = t & 63;       // 0..63
    const float* svf = (const float*)s_v;
    float r = 0.f;
#pragma unroll
    for (int w2 = 0; w2 < 8; ++w2) r += svf[w2 * (TI * 64) + i * 64 + d];
    float ssum = 0.f;
#pragma unroll
    for (int w2 = 0; w2 < 8; ++w2) ssum += s_red[w2][i];
    out[((size_t)b * LL + (i0 + i)) * DD + d] = r * (1.0f / (ssum + 1e-8f));
}

// ---------------------------------------------------------------------------
extern "C" void kernel_launch(void* const* d_in, const int* in_sizes, int n_in,
                              void* d_out, int out_size, void* d_ws, size_t ws_size,
                              hipStream_t stream) {
    const float* inp = (const float*)d_in[0];
    const float* Wt  = (const float*)d_in[1];
    const float* Wx  = (const float*)d_in[2];
    const float* Wa  = (const float*)d_in[3];
    const float* bh  = (const float*)d_in[4];
    // d_in[5] = ba (cancels in softmax), d_in[6] = attention_width (dead code)
    float* out = (float*)d_out;

    float* Eq  = (float*)d_ws;                      // B*L*U floats = 512 KB
    float* Ekt = Eq + (size_t)BB * LL * UU;         // transposed Ek, 512 KB

    precompute_kernel<<<BB * LL / PR, 512, 0, stream>>>(inp, Wt, Wx, bh, Eq, Ekt);
    attn_kernel<<<BB * LL / TI, NT, 0, stream>>>(Eq, Ekt, inp, Wa, out);
}

// Round 5
// 88.588 us; speedup vs baseline: 1.0224x; 1.0224x over previous
//
#include <hip/hip_runtime.h>

// Problem dims (fixed by reference)
#define BB 4
#define LL 1024
#define DD 64
#define UU 32
#define TI 8     // query rows per block (attn)
#define NT 512   // threads per block (8 waves)
#define PR 16    // rows per precompute block

// ---------------------------------------------------------------------------
// Packed fp32 via compiler-selected VOP3P: on gfx90a+ LLVM lowers <2 x float>
// fma/mul to v_pk_fma_f32 / v_pk_mul_f32 (2 fp32 ops per issue slot — the
// only path to the 157 TF fp32 peak; scalar v_fma is half rate). No inline
// asm: correctness identical to scalar IEEE fma per lane.
// ---------------------------------------------------------------------------
typedef float f32x2 __attribute__((ext_vector_type(2)));
#define FMA2(a, b, c) __builtin_elementwise_fma((a), (b), (c))
static __device__ __forceinline__ f32x2 splat2(float x) { return (f32x2){x, x}; }

// ---------------------------------------------------------------------------
// K1: Eq[b,l,u] = exp(2*(inp@Wt + bh))   (layout [row][u], scalar-loaded later)
//     Ekt[b,u4,j] = float4 of exp(2*(inp@Wx))  (TRANSPOSED: lane-consecutive
//     j -> coalesced float4 loads in attn phase A)
// tanh(q+k+bh) = 1 - 2/(1 + Eq*Ek)
// 16 rows/block, 512 threads, 256 blocks (launch/latency-dominated kernel).
// ---------------------------------------------------------------------------
__global__ __launch_bounds__(512) void precompute_kernel(
    const float* __restrict__ inp, const float* __restrict__ Wt,
    const float* __restrict__ Wx, const float* __restrict__ bh,
    float* __restrict__ Eq, float* __restrict__ Ekt)
{
    __shared__ float s_in[PR][DD];      // 4 KB
    __shared__ float s_wt[DD][UU];      // 8 KB
    __shared__ float s_wx[DD][UU];      // 8 KB
    __shared__ float s_ek[PR][36];      // padded: conflict-free b128 reads
    int t = threadIdx.x;
    int row0 = blockIdx.x * PR;
    ((float4*)s_wt)[t] = ((const float4*)Wt)[t];          // 512 float4 each
    ((float4*)s_wx)[t] = ((const float4*)Wx)[t];
    if (t < 256)
        ((float4*)s_in)[t] = ((const float4*)(inp + (size_t)row0 * DD))[t];
    __syncthreads();
    int r = t >> 5;     // 0..15
    int u = t & 31;
    size_t row = row0 + r;
    float q = 0.f, k = 0.f;
#pragma unroll
    for (int d = 0; d < DD; ++d) {
        float x = s_in[r][d];
        q = fmaf(x, s_wt[d][u], q);
        k = fmaf(x, s_wx[d][u], k);
    }
    Eq[row * UU + u] = __expf(2.f * (q + bh[u]));
    s_ek[r][u] = __expf(2.f * k);
    __syncthreads();
    // transposed write: Ekt[(b*8 + u4)*LL + l] (float4 units)
    if (t < 128) {
        int u4 = t >> 4, r2 = t & 15;
        float4 v = *(const float4*)(&s_ek[r2][u4 * 4]);
        size_t gr = row0 + r2;
        size_t bb_ = gr >> 10, l = gr & 1023;
        ((float4*)Ekt)[(bb_ * 8 + u4) * LL + l] = v;
    }
}

// ---------------------------------------------------------------------------
// K2: fused scores -> softmax -> v, TI=8 rows/block, 512 threads.
// grid = B*L/TI = 512 blocks (2/CU).
// v6 = v4 Phase A (common-denominator quad: 14 pk + 2 rcp per (i,u4) —
// rcp-minimal; v5's regroup added 2 TRANS (quarter-rate, ~8cy) to save 2 pk
// (~4cy), a measured +1.9us regression) + v5's Phase B rolling x-prefetch
// + v5's PR=16 precompute.
// ---------------------------------------------------------------------------
__global__ __launch_bounds__(NT, 4) void attn_kernel(
    const float* __restrict__ Eq, const float* __restrict__ Ekt,
    const float* __restrict__ inp, const float* __restrict__ Wa,
    float* __restrict__ out)
{
    __shared__ float s_a0[LL][4];          // 16 KB: a_unnorm[j][i0..3]
    __shared__ float s_a1[LL][4];          // 16 KB: a_unnorm[j][i4..7]
    __shared__ float4 s_v[8][TI][16];      // 16 KB: v partials [wave][i][dq]
    __shared__ float s_red[8][TI];         // wave partial sums

    int t  = threadIdx.x;
    int w  = t >> 6;                    // wave 0..7
    int b  = blockIdx.x >> 7;
    int i0 = (blockIdx.x & 127) * TI;

    const float4* ektb = (const float4*)Ekt + (size_t)b * 8 * LL;
    const float*  eqb  = Eq + ((size_t)(b * LL + i0)) * UU;   // block-uniform

    // ---------------- Phase A: scores, Ek register-resident as jj-pairs -----
    f32x2 ekp[8][4];                    // ekp[u4][c] = {Ek[j=t][c], Ek[j=t+512][c]}
#pragma unroll
    for (int u4 = 0; u4 < 8; ++u4) {
        float4 e0 = ektb[u4 * LL + t];
        float4 e1 = ektb[u4 * LL + NT + t];
        ekp[u4][0] = (f32x2){e0.x, e1.x};
        ekp[u4][1] = (f32x2){e0.y, e1.y};
        ekp[u4][2] = (f32x2){e0.z, e1.z};
        ekp[u4][3] = (f32x2){e0.w, e1.w};
    }

    const f32x2 ones = (f32x2){1.f, 1.f};
    f32x2 acc2[TI];
#pragma unroll
    for (int i = 0; i < TI; ++i) {
        acc2[i] = (f32x2){0.f, 0.f};
        const float* eqq = eqb + i * UU;                  // uniform s_loads
#pragma unroll
        for (int u4 = 0; u4 < 8; ++u4) {
            const float* waq = Wa + u4 * 4;               // uniform, CSEd
            f32x2 p = FMA2(splat2(eqq[u4 * 4 + 0]), ekp[u4][0], ones);
            f32x2 q = FMA2(splat2(eqq[u4 * 4 + 1]), ekp[u4][1], ones);
            f32x2 r = FMA2(splat2(eqq[u4 * 4 + 2]), ekp[u4][2], ones);
            f32x2 s = FMA2(splat2(eqq[u4 * 4 + 3]), ekp[u4][3], ones);
            // n01 = wa0*q + wa1*p ; n23 = wa2*s + wa3*r
            f32x2 n01 = FMA2(splat2(waq[0]), q, splat2(waq[1]) * p);
            f32x2 n23 = FMA2(splat2(waq[2]), s, splat2(waq[3]) * r);
            f32x2 pq  = p * q;
            f32x2 rs2 = r * s;
            f32x2 num = FMA2(n01, rs2, n23 * pq);
            f32x2 den = pq * rs2;                         // <= ~4e22, safe fp32
            f32x2 rcpd;
            rcpd.x = __builtin_amdgcn_rcpf(den.x);
            rcpd.y = __builtin_amdgcn_rcpf(den.y);
            acc2[i] = FMA2(num, rcpd, acc2[i]);
        }
    }

    // ---------------- exp (no max-sub: |arg| <= ~6) + single sum reduce -----
    float wsum[TI];
#pragma unroll
    for (int i = 0; i < TI; ++i) {
        float e0 = __expf(-2.f * acc2[i].x);
        float e1 = __expf(-2.f * acc2[i].y);
        acc2[i].x = e0;
        acc2[i].y = e1;
        float s = e0 + e1;
#pragma unroll
        for (int mm = 32; mm >= 1; mm >>= 1) s += __shfl_xor(s, mm, 64);
        wsum[i] = s;
    }
    if ((t & 63) == 0) {
#pragma unroll
        for (int i = 0; i < TI; ++i) s_red[w][i] = wsum[i];
    }

    // Phase-B x prefetch: issue BEFORE B1 so the barrier's vmcnt drain
    // overlaps staging; values stay in VGPRs (16 regs, ekp dead by now).
    int dq = t & 15;        // d-quad
    int g  = t >> 4;        // j-group 0..31
    const float4* inp4 = (const float4*)(inp + (size_t)b * LL * DD);
    float4 xpre[4];
#pragma unroll
    for (int pf = 0; pf < 4; ++pf)
        xpre[pf] = inp4[((pf * 32 + g) * 16) + dq];

    // stage UNNORMALIZED exp (normalization deferred to final output scale)
    {
        float4 lo, hi;
        lo.x = acc2[0].x; lo.y = acc2[1].x; lo.z = acc2[2].x; lo.w = acc2[3].x;
        hi.x = acc2[4].x; hi.y = acc2[5].x; hi.z = acc2[6].x; hi.w = acc2[7].x;
        *(float4*)(&s_a0[t][0]) = lo;
        *(float4*)(&s_a1[t][0]) = hi;
        lo.x = acc2[0].y; lo.y = acc2[1].y; lo.z = acc2[2].y; lo.w = acc2[3].y;
        hi.x = acc2[4].y; hi.y = acc2[5].y; hi.z = acc2[6].y; hi.w = acc2[7].y;
        *(float4*)(&s_a0[NT + t][0]) = lo;
        *(float4*)(&s_a1[NT + t][0]) = hi;
    }
    __syncthreads();                                             // B1

    // ---------------- Phase B: v = ex @ inputs (a-paired packed fp32) -------
    // vac[c][p] = { sum_j a[2p]  * x_c , sum_j a[2p+1] * x_c }
    f32x2 vac[4][4];
#pragma unroll
    for (int c = 0; c < 4; ++c)
#pragma unroll
        for (int p_ = 0; p_ < 4; ++p_) vac[c][p_] = (f32x2){0.f, 0.f};

#pragma unroll
    for (int jj = 0; jj < 32; ++jj) {
        int j = jj * 32 + g;
        float4 x = xpre[jj & 3];
        if (jj + 4 < 32)
            xpre[jj & 3] = inp4[(((jj + 4) * 32 + g) * 16) + dq];
        float4 a0 = *(const float4*)(&s_a0[j][0]);   // b128 broadcast
        float4 a1 = *(const float4*)(&s_a1[j][0]);
        f32x2 ap0 = (f32x2){a0.x, a0.y};             // natural reg pairs
        f32x2 ap1 = (f32x2){a0.z, a0.w};
        f32x2 ap2 = (f32x2){a1.x, a1.y};
        f32x2 ap3 = (f32x2){a1.z, a1.w};
        f32x2 xs;
        xs = splat2(x.x);
        vac[0][0] = FMA2(ap0, xs, vac[0][0]); vac[0][1] = FMA2(ap1, xs, vac[0][1]);
        vac[0][2] = FMA2(ap2, xs, vac[0][2]); vac[0][3] = FMA2(ap3, xs, vac[0][3]);
        xs = splat2(x.y);
        vac[1][0] = FMA2(ap0, xs, vac[1][0]); vac[1][1] = FMA2(ap1, xs, vac[1][1]);
        vac[1][2] = FMA2(ap2, xs, vac[1][2]); vac[1][3] = FMA2(ap3, xs, vac[1][3]);
        xs = splat2(x.z);
        vac[2][0] = FMA2(ap0, xs, vac[2][0]); vac[2][1] = FMA2(ap1, xs, vac[2][1]);
        vac[2][2] = FMA2(ap2, xs, vac[2][2]); vac[2][3] = FMA2(ap3, xs, vac[2][3]);
        xs = splat2(x.w);
        vac[3][0] = FMA2(ap0, xs, vac[3][0]); vac[3][1] = FMA2(ap1, xs, vac[3][1]);
        vac[3][2] = FMA2(ap2, xs, vac[3][2]); vac[3][3] = FMA2(ap3, xs, vac[3][3]);
    }

    // unwind a-pairing back to per-row float4s: v[i].c = vac[c][i>>1][i&1]
    float4 v[TI];
#pragma unroll
    for (int i = 0; i < TI; ++i) {
        int p_ = i >> 1;
        if (i & 1)
            v[i] = (float4){vac[0][p_].y, vac[1][p_].y, vac[2][p_].y, vac[3][p_].y};
        else
            v[i] = (float4){vac[0][p_].x, vac[1][p_].x, vac[2][p_].x, vac[3][p_].x};
    }

    // reduce 4 j-groups within each wave (lanes differ in bits 4,5 of t)
#pragma unroll
    for (int i = 0; i < TI; ++i) {
        v[i].x += __shfl_xor(v[i].x, 16, 64); v[i].y += __shfl_xor(v[i].y, 16, 64);
        v[i].z += __shfl_xor(v[i].z, 16, 64); v[i].w += __shfl_xor(v[i].w, 16, 64);
        v[i].x += __shfl_xor(v[i].x, 32, 64); v[i].y += __shfl_xor(v[i].y, 32, 64);
        v[i].z += __shfl_xor(v[i].z, 32, 64); v[i].w += __shfl_xor(v[i].w, 32, 64);
    }
    if ((t & 63) < 16) {
#pragma unroll
        for (int i = 0; i < TI; ++i) s_v[w][i][dq] = v[i];
    }
    __syncthreads();                                             // B2

    // final cross-wave reduce + deferred normalization + coalesced store
    int i = t >> 6;       // 0..7
    int d = t & 63;       // 0..63
    const float* svf = (const float*)s_v;
    float r = 0.f;
#pragma unroll
    for (int w2 = 0; w2 < 8; ++w2) r += svf[w2 * (TI * 64) + i * 64 + d];
    float ssum = 0.f;
#pragma unroll
    for (int w2 = 0; w2 < 8; ++w2) ssum += s_red[w2][i];
    out[((size_t)b * LL + (i0 + i)) * DD + d] = r * (1.0f / (ssum + 1e-8f));
}

// ---------------------------------------------------------------------------
extern "C" void kernel_launch(void* const* d_in, const int* in_sizes, int n_in,
                              void* d_out, int out_size, void* d_ws, size_t ws_size,
                              hipStream_t stream) {
    const float* inp = (const float*)d_in[0];
    const float* Wt  = (const float*)d_in[1];
    const float* Wx  = (const float*)d_in[2];
    const float* Wa  = (const float*)d_in[3];
    const float* bh  = (const float*)d_in[4];
    // d_in[5] = ba (cancels in softmax), d_in[6] = attention_width (dead code)
    float* out = (float*)d_out;

    float* Eq  = (float*)d_ws;                      // B*L*U floats = 512 KB
    float* Ekt = Eq + (size_t)BB * LL * UU;         // transposed Ek, 512 KB

    precompute_kernel<<<BB * LL / PR, 512, 0, stream>>>(inp, Wt, Wx, bh, Eq, Ekt);
    attn_kernel<<<BB * LL / TI, NT, 0, stream>>>(Eq, Ekt, inp, Wa, out);
}